// Round 3
// baseline (242.074 us; speedup 1.0000x reference)
//
#include <hip/hip_runtime.h>

// GAMSmooth: out[b,l,f] = (X_spline @ kernel)[idx[b,l], f] + bias[f]
// N_UNIQUE=10000, N_BASES=10, FILTERS=16, B=32, L=100000
// Memory-bound: 204.8 MB fp32 output write dominates. dur_us also contains
// ~160 us of harness reset traffic (819 MB ws poison + 205 MB out poison)
// that we cannot control.
//   kernel 1: tiny matmul+bias -> shrunk table in d_ws (640 KB, L2-resident)
//   kernel 2: grid-stride gather; 4 lanes per element, one float4 each,
//             8 float4 stores per thread (6250 blocks, zero tail), unroll x2
//             for two independent idx->table->store chains in flight.

#define N_UNIQUE 10000
#define N_BASES  10
#define FILTERS  16

typedef float f32x4 __attribute__((ext_vector_type(4)));

__global__ __launch_bounds__(256) void gam_shrunk_kernel(
    const float* __restrict__ X, const float* __restrict__ K,
    const float* __restrict__ bias, float* __restrict__ shrunk) {
  __shared__ float sK[N_BASES * FILTERS];
  __shared__ float sB[FILTERS];
  int t = threadIdx.x;
  if (t < N_BASES * FILTERS) sK[t] = K[t];
  if (t < FILTERS) sB[t] = bias[t];
  __syncthreads();
  int u = blockIdx.x * 256 + t;
  if (u >= N_UNIQUE) return;

  float acc[FILTERS];
#pragma unroll
  for (int f = 0; f < FILTERS; ++f) acc[f] = sB[f];
#pragma unroll
  for (int b = 0; b < N_BASES; ++b) {
    float x = X[u * N_BASES + b];
#pragma unroll
    for (int f = 0; f < FILTERS; ++f) acc[f] += x * sK[b * FILTERS + f];
  }
  // Regular (cacheable) stores: we WANT the table resident in L2.
  f32x4* dst = (f32x4*)(shrunk + (size_t)u * FILTERS);
#pragma unroll
  for (int q = 0; q < 4; ++q) {
    f32x4 v = {acc[4 * q], acc[4 * q + 1], acc[4 * q + 2], acc[4 * q + 3]};
    dst[q] = v;
  }
}

// Grid-stride gather. gid indexes float4s of out; 4 consecutive lanes cover
// one idx element's 16 filters -> consecutive lanes store consecutive 16 B
// (perfect coalescing), and their table reads hit one 64 B line.
// Launched with blocks*256 * ITERS == total4 exactly (no tail checks).
__global__ __launch_bounds__(256) void gam_gather_kernel(
    const int* __restrict__ idx, const f32x4* __restrict__ shrunk4,
    f32x4* __restrict__ out4, int stride /* = gridDim.x*256 */) {
  int gid = blockIdx.x * 256 + threadIdx.x;
#pragma unroll
  for (int it = 0; it < 4; ++it) {  // 4 iters x unroll 2 = 8 stores/thread
    int g0 = gid + (2 * it) * stride;
    int g1 = g0 + stride;
    // two independent chains: both loads issued before either store
    int u0 = __builtin_nontemporal_load(idx + (g0 >> 2));
    int u1 = __builtin_nontemporal_load(idx + (g1 >> 2));
    f32x4 v0 = shrunk4[(size_t)u0 * 4 + (g0 & 3)];
    f32x4 v1 = shrunk4[(size_t)u1 * 4 + (g1 & 3)];
    __builtin_nontemporal_store(v0, out4 + g0);
    __builtin_nontemporal_store(v1, out4 + g1);
  }
}

extern "C" void kernel_launch(void* const* d_in, const int* in_sizes, int n_in,
                              void* d_out, int out_size, void* d_ws, size_t ws_size,
                              hipStream_t stream) {
  const int*   idx  = (const int*)d_in[0];    // [B, L]
  const float* X    = (const float*)d_in[1];  // [N_UNIQUE, N_BASES]
  const float* K    = (const float*)d_in[2];  // [N_BASES, FILTERS]
  const float* bias = (const float*)d_in[3];  // [FILTERS]
  float* out    = (float*)d_out;              // [B, L, FILTERS] fp32
  float* shrunk = (float*)d_ws;               // 10000*16 fp32 = 640 KB

  // Kernel 1: shrunk = X @ K + bias  (ws re-poisoned every launch -> must
  // rerun every call; ~5 us).
  gam_shrunk_kernel<<<(N_UNIQUE + 255) / 256, 256, 0, stream>>>(X, K, bias, shrunk);

  // Kernel 2: grid-stride gather. total4 = B*L*4 = 12,800,000 float4s.
  // 6250 blocks x 256 threads = 1.6M threads x 8 stores = exact cover.
  const int blocks = 6250;
  const int stride = blocks * 256;  // 1,600,000
  gam_gather_kernel<<<blocks, 256, 0, stream>>>(idx, (const f32x4*)shrunk,
                                                (f32x4*)out, stride);
}